// Round 1
// baseline (15719.135 us; speedup 1.0000x reference)
//
#include <hip/hip_runtime.h>

// Problem dims
constexpr int TSTEPS = 512;
constexpr int FDIM   = 128;
constexpr int HDIM   = 256;
// Decomposition: 16 groups x 16 rows; 16 slices x 16 hidden units (x4 gates = 64 cols)
constexpr int NG  = 16;   // row groups
constexpr int RG  = 16;   // rows per group
constexpr int NSL = 16;   // slices (= blocks per group)
constexpr int JJ  = 16;   // hidden units per slice
constexpr int CB  = 64;   // columns per block (4 gates * JJ)
constexpr int KT  = HDIM + FDIM;  // 384 merged K (recurrent + input proj)
constexpr int KW  = KT / 4;       // 96 per wave (4 waves/block)

// Workspace layout: [0..255]: 16 uint barrier counters (padded); then h double-buffer
constexpr size_t HBUF_OFF    = 256;                          // bytes
constexpr size_t HBUF_FLOATS = 2ull * NG * HDIM * RG;        // 131072 floats
constexpr size_t WS_NEED     = HBUF_OFF + HBUF_FLOATS * 4;   // ~512.25 KB

__device__ __forceinline__ float sigmf(float z) { return 1.f / (1.f + __expf(-z)); }
__device__ __forceinline__ float tanhf_fast(float z) {
    float a = fabsf(z);
    float e = __expf(-2.f * a);
    float r = (1.f - e) / (1.f + e);
    return z < 0.f ? -r : r;
}

// Persistent LSTM kernel: 256 blocks (1/CU) x 256 threads (4 waves).
// Block (g,s): rows [16g,16g+16), hidden units [16s,16s+16) (all 4 gates).
// Weights resident in VGPRs (lane = column, wave = K-quarter).
// h exchanged via agent-scope (L2-bypassing) stores + per-group phase barrier.
extern "C" __global__ void __launch_bounds__(256, 1)
lstm_persist(const float* __restrict__ x, const float* __restrict__ kern,
             const float* __restrict__ rker, float* __restrict__ hbuf,
             unsigned* __restrict__ cnt_base)
{
    const int g    = blockIdx.x & 15;
    const int s    = blockIdx.x >> 4;   // same-group blocks share blockIdx%8 -> XCD affinity
    const int tid  = threadIdx.x;
    const int wave = tid >> 6;
    const int lane = tid & 63;

    __shared__ float hs[KT * RG];       // [k'][r] staging: h rows 0..255, x rows 256..383
    __shared__ float part[4 * CB * RG]; // [wave][c][r] partial z

    unsigned* cnt = cnt_base + g;
    float* hb0 = hbuf + (size_t)g * (HDIM * RG);
    float* hb1 = hbuf + (size_t)(NG * HDIM * RG) + (size_t)g * (HDIM * RG);

    // ---- Resident weights: lane = column c in [0,64); col = gate*256 + 16s + jj
    const int c    = lane;
    const int gate = c >> 4;
    const int jjc  = c & 15;
    const int colg = gate * HDIM + s * JJ + jjc;
    float wreg[KW];
#pragma unroll
    for (int i = 0; i < KW; ++i) {
        int kp = wave * KW + i;
        wreg[i] = (kp < HDIM) ? rker[(size_t)kp * (4 * HDIM) + colg]
                              : kern[(size_t)(kp - HDIM) * (4 * HDIM) + colg];
    }

    // ---- Nonlinearity mapping: thread <-> (row rr, hidden jr)
    const int rr = tid & 15;
    const int jr = tid >> 4;
    float cstate = 0.f;
    const int hw_off = (s * JJ + jr) * RG + rr;  // [k][r] within group block

    const float* xg = x + (size_t)(g * RG) * TSTEPS * FDIM;

#pragma unroll 1
    for (int t = 0; t < TSTEPS; ++t) {
        const int cur = t & 1;
        float* hb_cur = cur ? hb1 : hb0;
        float* hb_nxt = cur ? hb0 : hb1;

        // ---- Stage x(t) -> hs[256+f][r]  (h-independent: overlaps barrier wait below)
        {
            int ci = tid;                       // chunk: r = ci>>5, fc = ci&31
            int r0 = ci >> 5, fc = ci & 31;
            const float4 xv = *reinterpret_cast<const float4*>(
                xg + ((size_t)r0 * TSTEPS + t) * FDIM + fc * 4);
            int kb = (HDIM + fc * 4) * RG + r0;
            hs[kb] = xv.x; hs[kb + RG] = xv.y; hs[kb + 2 * RG] = xv.z; hs[kb + 3 * RG] = xv.w;
        }
        {
            int ci = tid + 256;
            int r0 = ci >> 5, fc = ci & 31;
            const float4 xv = *reinterpret_cast<const float4*>(
                xg + ((size_t)r0 * TSTEPS + t) * FDIM + fc * 4);
            int kb = (HDIM + fc * 4) * RG + r0;
            hs[kb] = xv.x; hs[kb + RG] = xv.y; hs[kb + 2 * RG] = xv.z; hs[kb + 3 * RG] = xv.w;
        }

        // ---- Group barrier: wait until all 16 blocks finished step t-1 (cnt >= 16*t)
        if (tid == 0) {
            const unsigned target = (unsigned)(NSL * t);
            while (__hip_atomic_load(cnt, __ATOMIC_RELAXED, __HIP_MEMORY_SCOPE_AGENT) < target) {
                __builtin_amdgcn_s_sleep(1);
            }
            (void)__hip_atomic_load(cnt, __ATOMIC_ACQUIRE, __HIP_MEMORY_SCOPE_AGENT); // inv caches
        }
        __syncthreads();

        // ---- Stage h(t) -> hs[k][r] (h(0) zeroed by memset; plain loads OK after acquire)
        {
            const float4* src = reinterpret_cast<const float4*>(hb_cur + (size_t)tid * RG);
            float4* dst = reinterpret_cast<float4*>(&hs[tid * RG]);
            dst[0] = src[0]; dst[1] = src[1]; dst[2] = src[2]; dst[3] = src[3];
        }
        __syncthreads();

        // ---- Inner GEMM: acc[r] = sum_k' w[k'][c] * hs[k'][r], k' covers rk then kernel
        float acc[16];
#pragma unroll
        for (int i = 0; i < 16; ++i) acc[i] = 0.f;
#pragma unroll
        for (int i = 0; i < KW; ++i) {
            const int kp = wave * KW + i;
            const float w = wreg[i];
            const float* hrow = &hs[kp * RG];
#pragma unroll
            for (int rq = 0; rq < 4; ++rq) {   // broadcast ds_read_b128 (uniform addr)
                const float4 hv = *reinterpret_cast<const float4*>(hrow + rq * 4);
                acc[rq * 4 + 0] += w * hv.x;
                acc[rq * 4 + 1] += w * hv.y;
                acc[rq * 4 + 2] += w * hv.z;
                acc[rq * 4 + 3] += w * hv.w;
            }
        }
        // ---- Write per-wave partials
#pragma unroll
        for (int rq = 0; rq < 4; ++rq) {
            *reinterpret_cast<float4*>(&part[(wave * CB + lane) * RG + rq * 4]) =
                make_float4(acc[rq * 4 + 0], acc[rq * 4 + 1], acc[rq * 4 + 2], acc[rq * 4 + 3]);
        }
        __syncthreads();

        // ---- Reduce 4 wave-partials, gates, cell update. thread <-> (rr, jr)
        float z0 = 0.f, z1 = 0.f, z2 = 0.f, z3 = 0.f;
#pragma unroll
        for (int w4 = 0; w4 < 4; ++w4) {
            z0 += part[(w4 * CB + 0 * JJ + jr) * RG + rr];
            z1 += part[(w4 * CB + 1 * JJ + jr) * RG + rr];
            z2 += part[(w4 * CB + 2 * JJ + jr) * RG + rr];
            z3 += part[(w4 * CB + 3 * JJ + jr) * RG + rr];
        }
        const float ai = sigmf(z0);
        const float af = sigmf(z1);
        const float ag = tanhf_fast(z2);
        const float ao = sigmf(z3);
        cstate = af * cstate + ai * ag;
        const float hnew = ao * tanhf_fast(cstate);

        // Agent-scope (sc1, L2-bypassing) store -> coherent point; visible cross-XCD
        __hip_atomic_store(hb_nxt + hw_off, hnew, __ATOMIC_RELAXED, __HIP_MEMORY_SCOPE_AGENT);

        __syncthreads();  // compiler drains vmcnt(0) before s_barrier -> stores complete
        if (tid == 0) {
            __hip_atomic_fetch_add(cnt, 1u, __ATOMIC_RELEASE, __HIP_MEMORY_SCOPE_AGENT);
        }
    }
    // t=511 wrote buffer 0 -> final h lives in hb0. Kernel boundary releases caches.
}

// Head: out[b] = relu(h[b]@w1 + b1) @ w2 + b2. One block per batch row.
extern "C" __global__ void __launch_bounds__(128, 1)
head_kernel(const float* __restrict__ hbuf0, const float* __restrict__ w1,
            const float* __restrict__ b1, const float* __restrict__ w2,
            const float* __restrict__ b2, float* __restrict__ out)
{
    const int b = blockIdx.x;
    const int g = b >> 4, r = b & 15;
    const int tid = threadIdx.x;
    __shared__ float lh[HDIM];
    __shared__ float hid[128];
    const float* hbg = hbuf0 + (size_t)g * (HDIM * RG);
    lh[tid]       = hbg[(size_t)tid * RG + r];
    lh[tid + 128] = hbg[(size_t)(tid + 128) * RG + r];
    hid[tid] = 0.f;
    __syncthreads();
    if (tid < 100) {
        float acc = b1[tid];
#pragma unroll 8
        for (int k = 0; k < HDIM; ++k) acc += lh[k] * w1[k * 100 + tid];
        hid[tid] = fmaxf(acc, 0.f);
    }
    __syncthreads();
    if (tid < 64) {
        float v = hid[tid] * w2[tid];
        const int j2 = tid + 64;
        v += (j2 < 100) ? hid[j2] * w2[j2] : 0.f;
        for (int off = 32; off; off >>= 1) v += __shfl_down(v, off, 64);
        if (tid == 0) out[b] = v + b2[0];
    }
}

extern "C" void kernel_launch(void* const* d_in, const int* in_sizes, int n_in,
                              void* d_out, int out_size, void* d_ws, size_t ws_size,
                              hipStream_t stream)
{
    const float* x    = (const float*)d_in[0];
    const float* kern = (const float*)d_in[1];
    const float* rker = (const float*)d_in[2];
    const float* w1   = (const float*)d_in[3];
    const float* b1   = (const float*)d_in[4];
    const float* w2   = (const float*)d_in[5];
    const float* b2   = (const float*)d_in[6];
    float* out = (float*)d_out;

    unsigned* cnt = (unsigned*)d_ws;
    float* hbuf   = (float*)((char*)d_ws + HBUF_OFF);

    // Zero barrier counters + h double-buffer (h0 = 0). Stream-ordered, capture-safe.
    hipMemsetAsync(d_ws, 0, WS_NEED, stream);

    lstm_persist<<<dim3(256), dim3(256), 0, stream>>>(x, kern, rker, hbuf, cnt);
    head_kernel<<<dim3(256), dim3(128), 0, stream>>>(hbuf /*buffer 0*/, w1, b1, w2, b2, out);
}